// Round 4
// baseline (662.523 us; speedup 1.0000x reference)
//
#include <hip/hip_runtime.h>
#include <cstdint>
#include <cstddef>
#include <math.h>

#define Hh 18
#define Tt 1024
#define WS 8                 // steps per phase
#define NW (Tt / WS)         // 128 phases of real work
#define RING 32              // xlb ring slots (2-window lag => span 22 < 32)

#define LC 1.44269504088896340736f   // log2(e)

__device__ __forceinline__ float sigm_(float u) {
    return __fdividef(1.f, 1.f + exp2f(-LC * u));
}
__device__ __forceinline__ float tanh_(float u) {
    return fmaf(-2.f, __fdividef(1.f, 1.f + exp2f((2.f * LC) * u)), 1.f);
}
// wave-uniform broadcast: lane k -> SGPR (k must be compile-time const via unroll)
__device__ __forceinline__ float rl_(float v, int k) {
    return __int_as_float(__builtin_amdgcn_readlane(__float_as_int(v), k));
}

// wave0: GRU recurrence + LSTM input-projection (piggybacks on same h broadcasts)
// wave1: LSTM recurrence + FC, two windows behind, fed through xlb ring.
__global__ __launch_bounds__(128, 2) void rnn_fused4(
    const float* __restrict__ x,
    const float* __restrict__ gWih, const float* __restrict__ gWhh,
    const float* __restrict__ gbih, const float* __restrict__ gbhh,
    const float* __restrict__ lWih, const float* __restrict__ lWhh,
    const float* __restrict__ lbih, const float* __restrict__ lbhh,
    const float* __restrict__ fcW, const float* __restrict__ fcb,
    float* __restrict__ out)
{
    const int tid  = threadIdx.x;
    const int wid  = tid >> 6;
    const int lane = tid & 63;
    const int b    = blockIdx.x;

    __shared__ __align__(16) float xlb[RING][80];   // LSTM input-proj ring

    const float* xb   = x   + (size_t)b * (Tt * Hh);
    float*       outp = out + (size_t)b * Tt;

    if (wid == 0) {
        // ---------------- wave0: GRU + LSTM x-proj ----------------
        const int rg = (lane < 54) ? lane : 0;      // GRU gate row (r/z/n)
        float wgi[Hh], wgh[Hh], wli[Hh], wli2[Hh];
        #pragma unroll
        for (int k = 0; k < Hh; k++) {
            wgi[k]  = gWih[rg * Hh + k];
            wgh[k]  = gWhh[rg * Hh + k];
            wli[k]  = lWih[lane * Hh + k];                              // LSTM Wih rows 0..63
            wli2[k] = (lane < 8) ? lWih[(64 + lane) * Hh + k] : 0.f;    // rows 64..71
        }
        const float bgi  = gbih[rg];
        const float bgh  = gbhh[rg];
        const float bli  = lbih[lane];
        const float bli2 = (lane < 8) ? lbih[64 + lane] : 0.f;

        const int i1 = (lane + 18) & 63;   // z
        const int i2 = (lane + 36) & 63;   // n
        const int i3 = (lane - 36) & 63;   // r -> n-lane

        float myh = 0.f;
        float cxA[Hh], cxB[Hh];
        #pragma unroll
        for (int k = 0; k < Hh; k++) cxA[k] = xb[k];   // x[0] (uniform -> scalar loads)

        auto gstep = [&](int t, float (&cur)[Hh], float (&nxt)[Hh]) {
            // prefetch x[t+1] (uniform address)
            if (t + 1 < Tt) {
                const float* xt = xb + (size_t)(t + 1) * Hh;
                #pragma unroll
                for (int k = 0; k < Hh; k++) nxt[k] = xt[k];
            }
            float ha = bgh, xa = bgi, xl = bli, xl2 = bli2;
            #pragma unroll
            for (int k = 0; k < Hh; k++) {
                const float sh = rl_(myh, k);          // h[t-1][k] broadcast (SGPR)
                ha  = fmaf(wgh[k],  sh,     ha);
                xa  = fmaf(wgi[k],  cur[k], xa);
                xl  = fmaf(wli[k],  sh,     xl);       // LSTM x-proj for step t-1
                xl2 = fmaf(wli2[k], sh,     xl2);
            }
            if (t > 0) {
                xlb[(t - 1) & (RING - 1)][lane] = xl;
                if (lane < 8) xlb[(t - 1) & (RING - 1)][64 + lane] = xl2;
            }
            const float sg = sigm_(xa + ha);           // r,z on their lanes
            const float rv = __shfl(sg, i3, 64);
            const float tn = tanh_(fmaf(rv, ha, xa));
            const float zz = __shfl(sg, i1, 64);
            const float nn = __shfl(tn, i2, 64);
            myh = fmaf(zz, myh - nn, nn);
        };

        for (int ph = 0; ph < NW + 2; ph++) {
            if (ph < NW) {
                const int base = ph * WS;
                #pragma unroll 1
                for (int j = 0; j < WS; j += 2) {
                    gstep(base + j,     cxA, cxB);
                    gstep(base + j + 1, cxB, cxA);
                }
            } else if (ph == NW) {
                // epilogue: LSTM x-proj for t = 1023 from final h
                float xl = bli, xl2 = bli2;
                #pragma unroll
                for (int k = 0; k < Hh; k++) {
                    const float sh = rl_(myh, k);
                    xl  = fmaf(wli[k],  sh, xl);
                    xl2 = fmaf(wli2[k], sh, xl2);
                }
                xlb[(Tt - 1) & (RING - 1)][lane] = xl;
                if (lane < 8) xlb[(Tt - 1) & (RING - 1)][64 + lane] = xl2;
            }
            __syncthreads();
        }
    } else {
        // ---------------- wave1: LSTM recurrence + FC ----------------
        const int rs = (lane < 8) ? (64 + lane) : 64;
        float wlh[Hh], wlh2[Hh];
        #pragma unroll
        for (int k = 0; k < Hh; k++) {
            wlh[k]  = lWhh[lane * Hh + k];     // rows 0..63 (i,f,g + o units 0..9)
            wlh2[k] = lWhh[rs * Hh + k];       // rows 64..71 (o units 10..17)
        }
        const float blh  = lbhh[lane];
        const float blh2 = lbhh[rs];

        const int i1 = (lane + 18) & 63;   // f
        const int i2 = (lane + 36) & 63;   // g
        const int i3 = (lane + 54) & 63;   // o primary
        const int i4 = (lane - 10) & 63;   // o secondary

        const bool  isg = (lane >= 36) && (lane < 54);
        const float kl  = isg ? (2.f * LC) : LC;
        const float Aa  = isg ? 2.f : 1.f;
        const float Bb  = isg ? -1.f : 0.f;

        const float fcw  = (lane < Hh) ? fcW[lane] : 0.f;
        const float fcbv = fcb[0];

        float myc = 0.f, myhl = 0.f;
        float o0 = 0.f, o1 = 0.f, o2 = 0.f, o3 = 0.f;

        for (int ph = 0; ph < NW + 2; ph++) {
            if (ph >= 2) {
                const int base = (ph - 2) * WS;
                #pragma unroll 2
                for (int j = 0; j < WS; j++) {
                    const int u = base + j;
                    float hla = blh, hl2 = blh2;
                    #pragma unroll
                    for (int k = 0; k < Hh; k++) {
                        const float sh = rl_(myhl, k);   // h_l[u-1][k] broadcast
                        hla = fmaf(wlh[k],  sh, hla);
                        hl2 = fmaf(wlh2[k], sh, hl2);
                    }
                    const float xl   = xlb[u & (RING - 1)][lane];
                    const float xl2v = xlb[u & (RING - 1)][64 + (lane & 7)];
                    const float a3 = fmaf(Aa, __fdividef(1.f, 1.f + exp2f(-kl * (xl + hla))), Bb);
                    const float a4 = sigm_(xl2v + hl2);
                    const float ff = __shfl(a3, i1, 64);
                    const float gg = __shfl(a3, i2, 64);
                    const float oa = __shfl(a3, i3, 64);
                    const float ob = __shfl(a4, i4, 64);
                    const float oo = (lane < 10) ? oa : ob;
                    const float cn = fmaf(ff, myc, a3 * gg);   // a3 on lanes<18 = i
                    myc = cn;
                    const float tc = tanh_(cn);
                    myhl = oo * tc;
                    // FC (lanes >= 18 contribute 0)
                    float fv = fcw * myhl;
                    fv += __shfl_xor(fv, 1, 64);
                    fv += __shfl_xor(fv, 2, 64);
                    fv += __shfl_xor(fv, 4, 64);
                    fv += __shfl_xor(fv, 8, 64);
                    fv += __shfl_xor(fv, 16, 64);
                    const float ov = fv + fcbv;
                    const int sm = u & 3;
                    if (sm == 0) o0 = ov; else if (sm == 1) o1 = ov;
                    else if (sm == 2) o2 = ov; else o3 = ov;
                    if (sm == 3 && lane == 0) {
                        float4 vv; vv.x = o0; vv.y = o1; vv.z = o2; vv.w = o3;
                        *reinterpret_cast<float4*>(outp + u - 3) = vv;
                    }
                }
            }
            __syncthreads();
        }
    }
}

extern "C" void kernel_launch(void* const* d_in, const int* in_sizes, int n_in,
                              void* d_out, int out_size, void* d_ws, size_t ws_size,
                              hipStream_t stream)
{
    (void)d_ws; (void)ws_size; (void)in_sizes; (void)n_in; (void)out_size;
    const float* xx   = (const float*)d_in[0];
    const float* gWih = (const float*)d_in[1];
    const float* gWhh = (const float*)d_in[2];
    const float* gbih = (const float*)d_in[3];
    const float* gbhh = (const float*)d_in[4];
    const float* lWih = (const float*)d_in[5];
    const float* lWhh = (const float*)d_in[6];
    const float* lbih = (const float*)d_in[7];
    const float* lbhh = (const float*)d_in[8];
    const float* fcW  = (const float*)d_in[9];
    const float* fcb  = (const float*)d_in[10];
    float* outp = (float*)d_out;

    dim3 grid(1024), block(128);
    hipLaunchKernelGGL(rnn_fused4, grid, block, 0, stream,
                       xx, gWih, gWhh, gbih, gbhh,
                       lWih, lWhh, lbih, lbhh, fcW, fcb, outp);
}

// Round 5
// 627.325 us; speedup vs baseline: 1.0561x; 1.0561x over previous
//
#include <hip/hip_runtime.h>
#include <cstdint>
#include <cstddef>
#include <math.h>

#define Hh 18
#define Tt 1024
#define WS 8                 // steps per phase/window
#define NW (Tt / WS)         // 128 windows

#define LC 1.44269504088896340736f   // log2(e)

__device__ __forceinline__ float sigm_(float u) {
    return __fdividef(1.f, 1.f + exp2f(-LC * u));
}
__device__ __forceinline__ float tanh_(float u) {
    return fmaf(-2.f, __fdividef(1.f, 1.f + exp2f((2.f * LC) * u)), 1.f);
}
// wave-uniform broadcast: lane k -> SGPR (k compile-time const via unroll)
__device__ __forceinline__ float rl_(float v, int k) {
    return __int_as_float(__builtin_amdgcn_readlane(__float_as_int(v), k));
}
// 18-float broadcast LDS row -> registers (rows 16B-aligned, pad 20)
__device__ __forceinline__ void ld18_(float* d, const float* s) {
    *(float4*)&d[0]  = *(const float4*)&s[0];
    *(float4*)&d[4]  = *(const float4*)&s[4];
    *(float4*)&d[8]  = *(const float4*)&s[8];
    *(float4*)&d[12] = *(const float4*)&s[12];
    d[16] = s[16]; d[17] = s[17];
}

// wave0: GRU recurrence + LSTM x-proj (readlane h-broadcast).
// wave1: LSTM recurrence + FC (2-window lag) + x staging + GRU input-proj (1 ahead).
__global__ __launch_bounds__(128, 2) void rnn_fused5(
    const float* __restrict__ x,
    const float* __restrict__ gWih, const float* __restrict__ gWhh,
    const float* __restrict__ gbih, const float* __restrict__ gbhh,
    const float* __restrict__ lWih, const float* __restrict__ lWhh,
    const float* __restrict__ lbih, const float* __restrict__ lbhh,
    const float* __restrict__ fcW, const float* __restrict__ fcb,
    float* __restrict__ out)
{
    const int tid  = threadIdx.x;
    const int wid  = tid >> 6;
    const int lane = tid & 63;
    const int b    = blockIdx.x;

    __shared__ __align__(16) float xab[16][64];   // GRU input-proj ring (slot = t&15)
    __shared__ __align__(16) float xlb[32][80];   // LSTM input-proj ring (slot = t&31)
    __shared__ __align__(16) float xst[WS][20];   // staged x window (wave1-private)

    const float* xb   = x   + (size_t)b * (Tt * Hh);
    float*       outp = out + (size_t)b * Tt;

    const int rg = (lane < 54) ? lane : 0;        // GRU gate row (r/z/n)
    const int rs = (lane < 8) ? (64 + lane) : 64; // LSTM secondary row

    // unified per-role weight registers
    float wA[Hh], wB[Hh], wC[Hh];
    float b0, b1, b2;
    if (wid == 0) {
        #pragma unroll
        for (int k = 0; k < Hh; k++) {
            wA[k] = gWhh[rg * Hh + k];                               // GRU Whh
            wB[k] = lWih[lane * Hh + k];                             // LSTM Wih primary
            wC[k] = (lane < 8) ? lWih[(64 + lane) * Hh + k] : 0.f;   // LSTM Wih secondary
        }
        b0 = gbhh[rg]; b1 = lbih[lane]; b2 = (lane < 8) ? lbih[64 + lane] : 0.f;
    } else {
        #pragma unroll
        for (int k = 0; k < Hh; k++) {
            wA[k] = lWhh[lane * Hh + k];                             // LSTM Whh primary
            wB[k] = lWhh[rs * Hh + k];                               // secondary
            wC[k] = gWih[rg * Hh + k];                               // GRU Wih
        }
        b0 = lbhh[lane]; b1 = lbhh[rs]; b2 = gbih[rg];
    }

    const int i1 = (lane + 18) & 63;   // z / f
    const int i2 = (lane + 36) & 63;   // n / g
    const int i3 = (wid == 0) ? ((lane - 36) & 63) : ((lane + 54) & 63); // r-src / o-src
    const int i4 = (lane - 10) & 63;   // o secondary src

    const bool  isg = (wid == 1) && (lane >= 36) && (lane < 54);
    const float kl  = isg ? (2.f * LC) : LC;
    const float Aa  = isg ? 2.f : 1.f;
    const float Bb  = isg ? -1.f : 0.f;
    const float fcw  = (wid == 1 && lane < Hh) ? fcW[lane] : 0.f;
    const float fcbv = fcb[0];

    // x staging lane->slot map (loop-invariant)
    const int j0 = lane, j1 = lane + 64, j2 = lane + 128;
    const int r0_ = j0 / Hh, c0_ = j0 % Hh;
    const int r1_ = j1 / Hh, c1_ = j1 % Hh;
    const int r2_ = j2 / Hh, c2_ = j2 % Hh;

    float px0 = 0.f, px1 = 0.f, px2 = 0.f;
    float myh = 0.f, myc = 0.f, myhl = 0.f;
    float o0 = 0.f, o1 = 0.f, o2 = 0.f, o3 = 0.f;

    // ---- prologue (wave1): stage x window 0, produce xab window 0, prefetch window 1
    if (wid == 1) {
        px0 = xb[j0]; px1 = xb[j1]; px2 = (lane < 16) ? xb[j2] : 0.f;
        xst[r0_][c0_] = px0; xst[r1_][c1_] = px1; if (lane < 16) xst[r2_][c2_] = px2;
        __builtin_amdgcn_wave_barrier();
        #pragma unroll
        for (int j = 0; j < WS; j++) {
            float xr[Hh]; ld18_(xr, xst[j]);
            float a0 = b2, a1 = 0.f;
            #pragma unroll
            for (int k = 0; k < Hh; k += 2) { a0 = fmaf(wC[k], xr[k], a0); a1 = fmaf(wC[k+1], xr[k+1], a1); }
            xab[j][lane] = a0 + a1;
        }
        const float* xw = xb + WS * Hh;
        px0 = xw[j0]; px1 = xw[j1]; if (lane < 16) px2 = xw[j2];
    }
    __syncthreads();

    for (int ph = 0; ph <= NW + 1; ph++) {
        if (wid == 1 && ph <= NW - 2) {
            // land window ph+1, prefetch window ph+2, produce xab window ph+1
            xst[r0_][c0_] = px0; xst[r1_][c1_] = px1; if (lane < 16) xst[r2_][c2_] = px2;
            if (ph + 2 <= NW - 1) {
                const float* xw = xb + (size_t)(ph + 2) * (WS * Hh);
                px0 = xw[j0]; px1 = xw[j1]; if (lane < 16) px2 = xw[j2];
            }
            __builtin_amdgcn_wave_barrier();
            const int tb = (ph + 1) * WS;
            #pragma unroll
            for (int j = 0; j < WS; j++) {
                float xr[Hh]; ld18_(xr, xst[j]);
                float a0 = b2, a1 = 0.f;
                #pragma unroll
                for (int k = 0; k < Hh; k += 2) { a0 = fmaf(wC[k], xr[k], a0); a1 = fmaf(wC[k+1], xr[k+1], a1); }
                xab[(tb + j) & 15][lane] = a0 + a1;
            }
        }

        if (wid == 0) {
            if (ph <= NW - 1) {
                const int base = ph * WS;
                #pragma unroll 2
                for (int j = 0; j < WS; j++) {
                    const int t = base + j;
                    const float xa = xab[t & 15][lane];        // gWih·x[t] + bih
                    float ha0 = b0, ha1 = 0.f, xl0 = b1, xl1 = 0.f, xl20 = b2, xl21 = 0.f;
                    #pragma unroll
                    for (int k = 0; k < Hh; k += 2) {
                        const float s0 = rl_(myh, k), s1 = rl_(myh, k + 1);
                        ha0  = fmaf(wA[k],   s0, ha0);  ha1  = fmaf(wA[k+1], s1, ha1);
                        xl0  = fmaf(wB[k],   s0, xl0);  xl1  = fmaf(wB[k+1], s1, xl1);
                        xl20 = fmaf(wC[k],   s0, xl20); xl21 = fmaf(wC[k+1], s1, xl21);
                    }
                    const float ha = ha0 + ha1;
                    if (t > 0) {                                // LSTM x-proj of h[t-1]
                        const int sl = (t - 1) & 31;
                        xlb[sl][lane] = xl0 + xl1;
                        if (lane < 8) xlb[sl][64 + lane] = xl20 + xl21;
                    }
                    const float sg = sigm_(xa + ha);
                    const float rv = __shfl(sg, i3, 64);
                    const float tn = tanh_(fmaf(rv, ha, xa));
                    const float zz = __shfl(sg, i1, 64);
                    const float nn = __shfl(tn, i2, 64);
                    myh = fmaf(zz, myh - nn, nn);
                }
            } else if (ph == NW) {
                // epilogue: LSTM x-proj for t=1023
                float xl0 = b1, xl1 = 0.f, xl20 = b2, xl21 = 0.f;
                #pragma unroll
                for (int k = 0; k < Hh; k += 2) {
                    const float s0 = rl_(myh, k), s1 = rl_(myh, k + 1);
                    xl0  = fmaf(wB[k],   s0, xl0);  xl1  = fmaf(wB[k+1], s1, xl1);
                    xl20 = fmaf(wC[k],   s0, xl20); xl21 = fmaf(wC[k+1], s1, xl21);
                }
                xlb[31][lane] = xl0 + xl1;
                if (lane < 8) xlb[31][64 + lane] = xl20 + xl21;
            }
        } else if (ph >= 2) {
            const int base = (ph - 2) * WS;
            #pragma unroll 2
            for (int j = 0; j < WS; j++) {
                const int u = base + j;
                const float xlv  = xlb[u & 31][lane];
                const float xl2v = xlb[u & 31][64 + (lane & 7)];
                float h0 = b0, h1 = 0.f, g0 = b1, g1 = 0.f;
                #pragma unroll
                for (int k = 0; k < Hh; k += 2) {
                    const float s0 = rl_(myhl, k), s1 = rl_(myhl, k + 1);
                    h0 = fmaf(wA[k],   s0, h0); h1 = fmaf(wA[k+1], s1, h1);
                    g0 = fmaf(wB[k],   s0, g0); g1 = fmaf(wB[k+1], s1, g1);
                }
                const float a3 = fmaf(Aa, __fdividef(1.f, 1.f + exp2f(-kl * (xlv + h0 + h1))), Bb);
                const float a4 = sigm_(xl2v + g0 + g1);
                const float ff = __shfl(a3, i1, 64);
                const float gg = __shfl(a3, i2, 64);
                const float oa = __shfl(a3, i3, 64);
                const float ob = __shfl(a4, i4, 64);
                const float oo = (lane < 10) ? oa : ob;
                const float cn = fmaf(ff, myc, a3 * gg);   // a3 on lanes<18 = i-gate
                myc = cn;
                myhl = oo * tanh_(cn);
                // FC (lanes >= 18 contribute 0)
                float fv = fcw * myhl;
                fv += __shfl_xor(fv, 1, 64);
                fv += __shfl_xor(fv, 2, 64);
                fv += __shfl_xor(fv, 4, 64);
                fv += __shfl_xor(fv, 8, 64);
                fv += __shfl_xor(fv, 16, 64);
                const float ov = fv + fcbv;
                const int sm = u & 3;
                if (sm == 0) o0 = ov; else if (sm == 1) o1 = ov;
                else if (sm == 2) o2 = ov; else o3 = ov;
                if (sm == 3 && lane == 0) {
                    float4 vv; vv.x = o0; vv.y = o1; vv.z = o2; vv.w = o3;
                    *reinterpret_cast<float4*>(outp + u - 3) = vv;
                }
            }
        }
        __syncthreads();
    }
}

extern "C" void kernel_launch(void* const* d_in, const int* in_sizes, int n_in,
                              void* d_out, int out_size, void* d_ws, size_t ws_size,
                              hipStream_t stream)
{
    (void)d_ws; (void)ws_size; (void)in_sizes; (void)n_in; (void)out_size;
    const float* xx   = (const float*)d_in[0];
    const float* gWih = (const float*)d_in[1];
    const float* gWhh = (const float*)d_in[2];
    const float* gbih = (const float*)d_in[3];
    const float* gbhh = (const float*)d_in[4];
    const float* lWih = (const float*)d_in[5];
    const float* lWhh = (const float*)d_in[6];
    const float* lbih = (const float*)d_in[7];
    const float* lbhh = (const float*)d_in[8];
    const float* fcW  = (const float*)d_in[9];
    const float* fcb  = (const float*)d_in[10];
    float* outp = (float*)d_out;

    dim3 grid(1024), block(128);
    hipLaunchKernelGGL(rnn_fused5, grid, block, 0, stream,
                       xx, gWih, gWhh, gbih, gbhh,
                       lWih, lWhh, lbih, lbhh, fcW, fcb, outp);
}